// Round 3
// baseline (14819.377 us; speedup 1.0000x reference)
//
#include <hip/hip_runtime.h>
#include <stdint.h>

#define T_LEN 4096
#define HID   400
#define G4    1600
#define KDIM  300
#define STACKN 32

__device__ __forceinline__ float fsig(float x){ return 1.f/(1.f + __expf(-x)); }
__device__ __forceinline__ float ftanh(float x){ float e = __expf(2.f*x); return 1.f - 2.f/(e+1.f); }

// ---------------- layer-0 xg GEMM with fused embedding gather (K=150, f32) ----------------
__global__ void __launch_bounds__(256) kgemm0(
    const int* __restrict__ xma, const int* __restrict__ xcpc, const int* __restrict__ xr,
    const float* __restrict__ em, const float* __restrict__ ec, const float* __restrict__ er,
    const float* __restrict__ W, const float* __restrict__ b1, const float* __restrict__ b2,
    float* __restrict__ XG)
{
  __shared__ float xs[8*152];
  const int t0 = blockIdx.x*8;
  const int tid = threadIdx.x;
  for (int idx = tid; idx < 8*150; idx += 256){
    int tt = idx / 150, k = idx - tt*150;
    int t = t0 + tt;
    float v;
    if (k < 50)       v = em[(size_t)xma[t]*50 + k];
    else if (k < 100) v = ec[(size_t)xcpc[t]*50 + (k-50)];
    else              v = er[(size_t)xr[t]*50 + (k-100)];
    xs[tt*152 + k] = v;
  }
  __syncthreads();
  int r = blockIdx.y*256 + tid;
  if (r >= G4) return;
  float acc[8];
  #pragma unroll
  for (int i=0;i<8;i++) acc[i]=0.f;
  const float2* wr = (const float2*)(W + (size_t)r*150);
  for (int k2=0;k2<75;k2++){
    float2 w = wr[k2];
    int k = 2*k2;
    #pragma unroll
    for (int tt=0;tt<8;tt++)
      acc[tt] += w.x*xs[tt*152+k] + w.y*xs[tt*152+k+1];
  }
  float bb = b1[r] + b2[r];
  #pragma unroll
  for (int tt=0;tt<8;tt++)
    XG[(size_t)(t0+tt)*G4 + r] = acc[tt] + bb;
}

// ---------------- layer-1 xg GEMM: XG = H0 @ Wih1.T + b1 + b2 (K=400, f32) ----------------
__global__ void __launch_bounds__(256) kgemm(
    const float* __restrict__ X, const float* __restrict__ W,
    const float* __restrict__ b1, const float* __restrict__ b2,
    float* __restrict__ XG)
{
  __shared__ float xs[8*400];
  const int t0 = blockIdx.x*8;
  const int tid = threadIdx.x;
  for (int idx = tid; idx < 8*400; idx += 256)
    xs[idx] = X[(size_t)t0*400 + idx];
  __syncthreads();
  int r = blockIdx.y*256 + tid;
  if (r >= G4) return;
  float acc[8];
  #pragma unroll
  for (int i=0;i<8;i++) acc[i]=0.f;
  const float4* wr = (const float4*)(W + (size_t)r*HID);
  for (int k4=0;k4<100;k4++){
    float4 w = wr[k4];
    #pragma unroll
    for (int tt=0;tt<8;tt++){
      const float4 x4 = *(const float4*)(xs + tt*400 + 4*k4);
      acc[tt] += w.x*x4.x + w.y*x4.y + w.z*x4.z + w.w*x4.w;
    }
  }
  float bb = b1[r] + b2[r];
  #pragma unroll
  for (int tt=0;tt<8;tt++)
    XG[(size_t)(t0+tt)*G4 + r] = acc[tt] + bb;
}

// ---------------- sequential LSTM scan: 16 WGs, weights-stationary in VGPRs ----------
// WG w owns rows {g*400 + w*25 + jj : g<4, jj<25}; publishes h[w*25..w*25+25).
// Handshake: hbuf[(t+1)&1][j] = {tag=t+1 (hi32), f32 h (lo32)} as one 64-bit agent atomic.
// Tags 1..T never collide with harness memset(0x00) or poison(0xAA) patterns.
__global__ void __launch_bounds__(512,1) kscan(
    const float* __restrict__ XG, const float* __restrict__ Whh,
    float* __restrict__ Hout, unsigned long long* hbuf, int T)
{
  const int w = blockIdx.x;          // 0..15
  const int tid = threadIdx.x;
  const int row_local = tid >> 2;    // 0..127
  const int part = tid & 3;          // k-slice of 100
  const bool mat = (row_local < 100);
  float wreg[100];
  if (mat){
    int gate = row_local / 25, jj = row_local % 25;
    int row = gate*400 + w*25 + jj;
    const float4* wr = (const float4*)(Whh + (size_t)row*HID) + part*25;
    #pragma unroll
    for (int i=0;i<25;i++){
      float4 v = wr[i];
      wreg[4*i]   = v.x; wreg[4*i+1] = v.y;
      wreg[4*i+2] = v.z; wreg[4*i+3] = v.w;
    }
  }
  __shared__ float lds_h[HID];
  __shared__ float lds_g[100];
  __shared__ float lds_hnew[25];
  const bool ew = (tid < 25);
  const int j = w*25 + tid;          // valid when ew
  float c = 0.f;

  for (int t=0; t<T; t++){
    // prefetch xg row values (independent of the handshake; hides global latency)
    float xgi=0.f, xgf=0.f, xgg=0.f, xgo=0.f;
    if (ew){
      const float* xrw = XG + (size_t)t*G4;
      xgi = xrw[j]; xgf = xrw[HID+j]; xgg = xrw[2*HID+j]; xgo = xrw[3*HID+j];
    }
    // stage h_{t-1} into LDS
    if (tid < HID){
      float hv = 0.f;
      if (t > 0){
        if (tid >= w*25 && tid < w*25+25){
          hv = lds_hnew[tid - w*25];               // own slice: no global round trip
        } else {
          const unsigned long long* src = hbuf + (size_t)(t&1)*HID + tid;
          unsigned long long ex;
          do { ex = __hip_atomic_load(src, __ATOMIC_RELAXED, __HIP_MEMORY_SCOPE_AGENT); }
          while ((unsigned)(ex >> 32) != (unsigned)t);
          union{unsigned u; float f;} cv; cv.u = (unsigned)ex; hv = cv.f;
        }
      }
      lds_h[tid] = hv;
    }
    __syncthreads();
    // matvec: each thread does a 100-wide slice of one row
    float sum = 0.f;
    if (mat){
      const float4* hp = (const float4*)(lds_h + part*100);
      #pragma unroll
      for (int i=0;i<25;i++){
        float4 h4 = hp[i];
        sum += wreg[4*i  ]*h4.x;
        sum += wreg[4*i+1]*h4.y;
        sum += wreg[4*i+2]*h4.z;
        sum += wreg[4*i+3]*h4.w;
      }
    }
    sum += __shfl_xor(sum, 1);
    sum += __shfl_xor(sum, 2);
    if (mat && part==0) lds_g[row_local] = sum;
    __syncthreads();
    // elementwise gate update for our 25 h-lanes
    if (ew){
      float gi = xgi + lds_g[tid];
      float gf = xgf + lds_g[25+tid];
      float gg = xgg + lds_g[50+tid];
      float go = xgo + lds_g[75+tid];
      float si = fsig(gi), sf = fsig(gf), so = fsig(go), tg = ftanh(gg);
      c = sf*c + si*tg;
      float h = so*ftanh(c);
      Hout[(size_t)t*HID + j] = h;
      lds_hnew[tid] = h;
      union{unsigned u; float f;} cv; cv.f = h;
      unsigned long long pk = ((unsigned long long)(unsigned)(t+1) << 32)
                            | (unsigned long long)cv.u;
      __hip_atomic_store(hbuf + (size_t)((t+1)&1)*HID + j, pk,
                         __ATOMIC_RELAXED, __HIP_MEMORY_SCOPE_AGENT);
    }
    __syncthreads();
  }
}

// ---------------- rtoken = RN @ fcW.T + fcb  (f32) ----------------
__global__ void __launch_bounds__(256) krtoken(
    const float* __restrict__ RN, const float* __restrict__ fcW,
    const float* __restrict__ fcb, float* __restrict__ out)
{
  __shared__ float xs[8*400];
  const int t0 = blockIdx.x*8;
  const int tid = threadIdx.x;
  for (int idx = tid; idx < 8*400; idx += 256)
    xs[idx] = RN[(size_t)t0*400 + idx];
  __syncthreads();
  if (tid >= 150) return;
  float acc[8];
  #pragma unroll
  for (int i=0;i<8;i++) acc[i]=0.f;
  const float4* wr = (const float4*)(fcW + (size_t)tid*400);
  for (int k4=0;k4<100;k4++){
    float4 w = wr[k4];
    #pragma unroll
    for (int tt=0;tt<8;tt++){
      const float4 x4 = *(const float4*)(xs + tt*400 + 4*k4);
      acc[tt] += w.x*x4.x + w.y*x4.y + w.z*x4.z + w.w*x4.w;
    }
  }
  float bb = fcb[tid];
  #pragma unroll
  for (int tt=0;tt<8;tt++)
    out[(size_t)(t0+tt)*150 + tid] = acc[tt] + bb;
}

// ---------------- per-t context scalar: v[t] = softmax0(actW@rnn+actb) * sigmoid(D@rnn) ----
__global__ void kfinal(const float* __restrict__ RN, const float* __restrict__ actW,
                       const float* __restrict__ actb, const float* __restrict__ Dp,
                       float* __restrict__ vbuf)
{
  int t = blockIdx.x, l = threadIdx.x;
  const float* r = RN + (size_t)t*HID;
  float s0=0.f, s1=0.f, s2=0.f, sd=0.f;
  for (int k=l; k<HID; k+=64){
    float rv = r[k];
    s0 += actW[k]*rv;
    s1 += actW[400+k]*rv;
    s2 += actW[800+k]*rv;
    sd += Dp[k]*rv;
  }
  #pragma unroll
  for (int o=1;o<64;o<<=1){
    s0 += __shfl_xor(s0,o); s1 += __shfl_xor(s1,o);
    s2 += __shfl_xor(s2,o); sd += __shfl_xor(sd,o);
  }
  if (l==0){
    s0 += actb[0]; s1 += actb[1]; s2 += actb[2];
    float m = fmaxf(s0, fmaxf(s1, s2));
    float e0 = __expf(s0-m), e1 = __expf(s1-m), e2 = __expf(s2-m);
    float p0 = e0/(e0+e1+e2);
    vbuf[t] = p0 * fsig(sd);
  }
}

// ---------------- context write: zero everything, slot0 = v[t] broadcast (f32) ----------------
// LAST kernel: deterministically overwrites the whole ctx region (which doubled as scratch).
// row = STACKN*HID f32 = 51,200 B = 3200 uint4; slot0 = 400 f32 = 100 uint4.
__global__ void kctx(const float* __restrict__ vbuf, uint4* __restrict__ ctx, int n16){
  int i = blockIdx.x*256 + threadIdx.x;
  int stride = gridDim.x*256;
  for (; i<n16; i+=stride){
    int t = i / 3200;
    int p = i - t*3200;
    uint4 z;
    if (p < 100){
      float v = vbuf[t];
      union{float f; uint32_t u;} cv; cv.f = v;
      z.x = z.y = z.z = z.w = cv.u;
    } else {
      z.x = z.y = z.z = z.w = 0u;
    }
    ctx[i] = z;
  }
}

// ---------------- key LSTM (1 step, h0=c0=0 so key_Whh is dead) + fc (f32) ----------------
__global__ void __launch_bounds__(512) kkey(
    const float* __restrict__ RN, const float* __restrict__ Wih,
    const float* __restrict__ bih, const float* __restrict__ bhh,
    const float* __restrict__ fcW, const float* __restrict__ fcb,
    float* __restrict__ out)
{
  __shared__ float rh[HID];
  __shared__ float gk[4*KDIM];
  __shared__ float hk[KDIM];
  int tid = threadIdx.x;
  if (tid < HID) rh[tid] = RN[(size_t)(T_LEN-1)*HID + tid];
  __syncthreads();
  for (int r = tid; r < 4*KDIM; r += 512){
    const float4* wr = (const float4*)(Wih + (size_t)r*HID);
    float acc = 0.f;
    for (int k4=0;k4<100;k4++){
      float4 w = wr[k4];
      const float4 x4 = *(const float4*)(rh + 4*k4);
      acc += w.x*x4.x + w.y*x4.y + w.z*x4.z + w.w*x4.w;
    }
    gk[r] = acc + bih[r] + bhh[r];
  }
  __syncthreads();
  if (tid < KDIM){
    float gi = gk[tid], gg = gk[2*KDIM+tid], go = gk[3*KDIM+tid];
    float cc = fsig(gi)*ftanh(gg);        // c0 = 0 -> forget-gate term vanishes
    hk[tid] = fsig(go)*ftanh(cc);
  }
  __syncthreads();
  if (tid < HID){
    const float4* wr = (const float4*)(fcW + (size_t)tid*KDIM);
    float acc = 0.f;
    for (int k4=0;k4<75;k4++){
      float4 w = wr[k4];
      const float4 x4 = *(const float4*)(hk + 4*k4);
      acc += w.x*x4.x + w.y*x4.y + w.z*x4.z + w.w*x4.w;
    }
    out[tid] = acc + fcb[tid];
  }
}

extern "C" void kernel_launch(void* const* d_in, const int* in_sizes, int n_in,
                              void* d_out, int out_size, void* d_ws, size_t ws_size,
                              hipStream_t stream)
{
  (void)in_sizes; (void)n_in; (void)ws_size;
  const int*   xr   = (const int*)d_in[0];
  const int*   xcpc = (const int*)d_in[1];
  const int*   xma  = (const int*)d_in[2];
  const float* em   = (const float*)d_in[3];
  const float* ec   = (const float*)d_in[4];
  const float* er   = (const float*)d_in[5];
  const float* Wih0 = (const float*)d_in[6];
  const float* Whh0 = (const float*)d_in[7];
  const float* bih0 = (const float*)d_in[8];
  const float* bhh0 = (const float*)d_in[9];
  const float* Wih1 = (const float*)d_in[10];
  const float* Whh1 = (const float*)d_in[11];
  const float* bih1 = (const float*)d_in[12];
  const float* bhh1 = (const float*)d_in[13];
  const float* fcW  = (const float*)d_in[14];
  const float* fcb  = (const float*)d_in[15];
  const float* actW = (const float*)d_in[16];
  const float* actb = (const float*)d_in[17];
  const float* Dp   = (const float*)d_in[18];
  const float* kWih = (const float*)d_in[19];
  /* d_in[20] key_Whh unused: h0 = 0 for the single key step */
  const float* kbih = (const float*)d_in[21];
  const float* kbhh = (const float*)d_in[22];
  const float* kfcW = (const float*)d_in[23];
  const float* kfcb = (const float*)d_in[24];

  // ---- tiny ws usage only (~29 KB): handshake bufs + per-t scalar ----
  char* ws = (char*)d_ws;
  unsigned long long* hbuf0 = (unsigned long long*)(ws);          // 2*400 u64 = 6400 B
  unsigned long long* hbuf1 = (unsigned long long*)(ws + 6400);   // 6400 B
  float* vbuf = (float*)(ws + 12800);                             // 4096 f32

  // ---- large scratch lives in the TAIL of d_out's ctx region; kctx rewrites it last ----
  float* out = (float*)d_out;
  char*  ob  = (char*)d_out;
  size_t total = (size_t)out_size * 4;                  // 212,174,400 bytes (f32 out)
  float* RN = (float*)(ob + total - 6553600);           // 4096*400 f32
  float* H0 = (float*)(ob + total - 2*6553600);         // 4096*400 f32
  float* XG = (float*)(ob + total - 2*6553600 - 26214400); // 4096*1600 f32

  float* rtok = out;                 // 4096*150
  float* ktok = out + 614400;        // 400
  uint4* ctxp = (uint4*)(ob + 614800u*4u);              // ctx region, 209,715,200 B
  int n16 = (int)((total - 614800u*4u) >> 4);           // 13,107,200

  dim3 gg(T_LEN/8, 7);
  kgemm0<<<gg,256,0,stream>>>(xma, xcpc, xr, em, ec, er, Wih0, bih0, bhh0, XG);
  kscan<<<16,512,0,stream>>>(XG, Whh0, H0, hbuf0, T_LEN);
  kgemm<<<gg,256,0,stream>>>(H0, Wih1, bih1, bhh1, XG);
  kscan<<<16,512,0,stream>>>(XG, Whh1, RN, hbuf1, T_LEN);
  krtoken<<<T_LEN/8,256,0,stream>>>(RN, fcW, fcb, rtok);
  kkey<<<1,512,0,stream>>>(RN, kWih, kbih, kbhh, kfcW, kfcb, ktok);
  kfinal<<<T_LEN,64,0,stream>>>(RN, actW, actb, Dp, vbuf);
  kctx<<<2048,256,0,stream>>>(vbuf, ctxp, n16);
}

// Round 4
// 8147.405 us; speedup vs baseline: 1.8189x; 1.8189x over previous
//
#include <hip/hip_runtime.h>
#include <stdint.h>

#define T_LEN 4096
#define HID   400
#define G4    1600
#define KDIM  300
#define STACKN 32

__device__ __forceinline__ float fsig(float x){ return 1.f/(1.f + __expf(-x)); }
__device__ __forceinline__ float ftanh(float x){ float e = __expf(2.f*x); return 1.f - 2.f/(e+1.f); }

// ---------------- layer-0 xg GEMM with fused embedding gather (K=150, f32) ----------------
__global__ void __launch_bounds__(256) kgemm0(
    const int* __restrict__ xma, const int* __restrict__ xcpc, const int* __restrict__ xr,
    const float* __restrict__ em, const float* __restrict__ ec, const float* __restrict__ er,
    const float* __restrict__ W, const float* __restrict__ b1, const float* __restrict__ b2,
    float* __restrict__ XG)
{
  __shared__ float xs[8*152];
  const int t0 = blockIdx.x*8;
  const int tid = threadIdx.x;
  for (int idx = tid; idx < 8*150; idx += 256){
    int tt = idx / 150, k = idx - tt*150;
    int t = t0 + tt;
    float v;
    if (k < 50)       v = em[(size_t)xma[t]*50 + k];
    else if (k < 100) v = ec[(size_t)xcpc[t]*50 + (k-50)];
    else              v = er[(size_t)xr[t]*50 + (k-100)];
    xs[tt*152 + k] = v;
  }
  __syncthreads();
  int r = blockIdx.y*256 + tid;
  if (r >= G4) return;
  float acc[8];
  #pragma unroll
  for (int i=0;i<8;i++) acc[i]=0.f;
  const float2* wr = (const float2*)(W + (size_t)r*150);
  for (int k2=0;k2<75;k2++){
    float2 w = wr[k2];
    int k = 2*k2;
    #pragma unroll
    for (int tt=0;tt<8;tt++)
      acc[tt] += w.x*xs[tt*152+k] + w.y*xs[tt*152+k+1];
  }
  float bb = b1[r] + b2[r];
  #pragma unroll
  for (int tt=0;tt<8;tt++)
    XG[(size_t)(t0+tt)*G4 + r] = acc[tt] + bb;
}

// ================== fused 2-layer pipelined LSTM scan ==================
// 48 WGs: [0,16) layer-0 recurrence; [16,32) FF (xg1 = Wih1 @ h0_t + biases);
// [32,48) layer-1 recurrence (writes RN).
// Tagged handshake: u64 {tag (hi32), f32 value (lo32)}, relaxed agent-scope atomics,
// depth-4 slot buffers (slot = tag & 3). Tags 1..T never collide with 0x00/0xAA fill.
__global__ void __launch_bounds__(512,1) kpipe(
    const float* __restrict__ XG0,
    const float* __restrict__ Whh0, const float* __restrict__ Whh1,
    const float* __restrict__ Wih1, const float* __restrict__ bih1,
    const float* __restrict__ bhh1,
    float* __restrict__ RN,
    unsigned long long* hbufA, unsigned long long* hbufB,
    unsigned long long* gbuf, int T)
{
  const int wid = blockIdx.x;
  const int tid = threadIdx.x;
  const int row_local = tid >> 2;    // 0..127 (100 used)
  const int part = tid & 3;          // k-slice of 100
  const bool mat = (row_local < 100);

  __shared__ float lds_h[HID];
  __shared__ float lds_g[100];
  __shared__ float lds_xg[100];
  __shared__ float lds_hnew[25];

  if (wid < 16){
    // ---------- layer-0 recurrence ----------
    const int w = wid;
    float wreg[100];
    if (mat){
      int gate = row_local/25, jj = row_local%25;
      int row = gate*400 + w*25 + jj;
      const float4* wr = (const float4*)(Whh0 + (size_t)row*HID) + part*25;
      #pragma unroll
      for (int i=0;i<25;i++){
        float4 v = wr[i];
        wreg[4*i]=v.x; wreg[4*i+1]=v.y; wreg[4*i+2]=v.z; wreg[4*i+3]=v.w;
      }
    }
    const bool ew = (tid < 25);
    const int j = w*25 + tid;
    float c = 0.f;
    for (int t=0; t<T; t++){
      float xgi=0.f, xgf=0.f, xgg=0.f, xgo=0.f;
      if (ew){
        const float* xrw = XG0 + (size_t)t*G4;
        xgi = xrw[j]; xgf = xrw[HID+j]; xgg = xrw[2*HID+j]; xgo = xrw[3*HID+j];
      }
      if (tid < HID){
        float hv = 0.f;
        if (t > 0){
          if (tid >= w*25 && tid < w*25+25){
            hv = lds_hnew[tid - w*25];
          } else {
            const unsigned long long* src = hbufA + (size_t)(t&3)*HID + tid;
            unsigned long long ex;
            do { ex = __hip_atomic_load(src, __ATOMIC_RELAXED, __HIP_MEMORY_SCOPE_AGENT); }
            while ((unsigned)(ex >> 32) != (unsigned)t);
            union{unsigned u; float f;} cv; cv.u = (unsigned)ex; hv = cv.f;
          }
        }
        lds_h[tid] = hv;
      }
      __syncthreads();
      float sum = 0.f;
      if (mat){
        const float4* hp = (const float4*)(lds_h + part*100);
        #pragma unroll
        for (int i=0;i<25;i++){
          float4 h4 = hp[i];
          sum += wreg[4*i]*h4.x + wreg[4*i+1]*h4.y + wreg[4*i+2]*h4.z + wreg[4*i+3]*h4.w;
        }
      }
      sum += __shfl_xor(sum, 1);
      sum += __shfl_xor(sum, 2);
      if (mat && part==0) lds_g[row_local] = sum;
      __syncthreads();
      if (ew){
        float gi = xgi + lds_g[tid];
        float gf = xgf + lds_g[25+tid];
        float gg = xgg + lds_g[50+tid];
        float go = xgo + lds_g[75+tid];
        float si = fsig(gi), sf = fsig(gf), so = fsig(go), tg = ftanh(gg);
        c = sf*c + si*tg;
        float h = so*ftanh(c);
        lds_hnew[tid] = h;
        union{unsigned u; float f;} cv; cv.f = h;
        unsigned long long pk = ((unsigned long long)(unsigned)(t+1) << 32) | (unsigned long long)cv.u;
        __hip_atomic_store(hbufA + (size_t)((t+1)&3)*HID + j, pk,
                           __ATOMIC_RELAXED, __HIP_MEMORY_SCOPE_AGENT);
      }
      __syncthreads();
    }
  } else if (wid < 32){
    // ---------- FF: xg1_t = Wih1(own 100 rows) @ h0_t + bih1 + bhh1 ----------
    const int f = wid - 16;
    float wreg[100];
    float bias = 0.f;
    int grow = 0;
    if (mat){
      int gate = row_local/25, jj = row_local%25;
      grow = gate*400 + f*25 + jj;
      const float4* wr = (const float4*)(Wih1 + (size_t)grow*HID) + part*25;
      #pragma unroll
      for (int i=0;i<25;i++){
        float4 v = wr[i];
        wreg[4*i]=v.x; wreg[4*i+1]=v.y; wreg[4*i+2]=v.z; wreg[4*i+3]=v.w;
      }
      if (part==0) bias = bih1[grow] + bhh1[grow];
    }
    for (int t=0; t<T; t++){
      if (tid < HID){
        const unsigned long long* src = hbufA + (size_t)((t+1)&3)*HID + tid;
        unsigned long long ex;
        do { ex = __hip_atomic_load(src, __ATOMIC_RELAXED, __HIP_MEMORY_SCOPE_AGENT); }
        while ((unsigned)(ex >> 32) != (unsigned)(t+1));
        union{unsigned u; float f;} cv; cv.u = (unsigned)ex;
        lds_h[tid] = cv.f;
      }
      __syncthreads();
      float sum = 0.f;
      if (mat){
        const float4* hp = (const float4*)(lds_h + part*100);
        #pragma unroll
        for (int i=0;i<25;i++){
          float4 h4 = hp[i];
          sum += wreg[4*i]*h4.x + wreg[4*i+1]*h4.y + wreg[4*i+2]*h4.z + wreg[4*i+3]*h4.w;
        }
      }
      sum += __shfl_xor(sum, 1);
      sum += __shfl_xor(sum, 2);
      if (mat && part==0){
        union{unsigned u; float f;} cv; cv.f = sum + bias;
        unsigned long long pk = ((unsigned long long)(unsigned)(t+1) << 32) | (unsigned long long)cv.u;
        __hip_atomic_store(gbuf + (size_t)((t+1)&3)*G4 + grow, pk,
                           __ATOMIC_RELAXED, __HIP_MEMORY_SCOPE_AGENT);
      }
      __syncthreads();
    }
  } else {
    // ---------- layer-1 recurrence ----------
    const int l = wid - 32;
    float wreg[100];
    if (mat){
      int gate = row_local/25, jj = row_local%25;
      int row = gate*400 + l*25 + jj;
      const float4* wr = (const float4*)(Whh1 + (size_t)row*HID) + part*25;
      #pragma unroll
      for (int i=0;i<25;i++){
        float4 v = wr[i];
        wreg[4*i]=v.x; wreg[4*i+1]=v.y; wreg[4*i+2]=v.z; wreg[4*i+3]=v.w;
      }
    }
    const bool ew = (tid < 25);
    const int j = l*25 + tid;
    float c = 0.f;
    for (int t=0; t<T; t++){
      if (tid < HID){
        float hv = 0.f;
        if (t > 0){
          if (tid >= l*25 && tid < l*25+25){
            hv = lds_hnew[tid - l*25];
          } else {
            const unsigned long long* src = hbufB + (size_t)(t&3)*HID + tid;
            unsigned long long ex;
            do { ex = __hip_atomic_load(src, __ATOMIC_RELAXED, __HIP_MEMORY_SCOPE_AGENT); }
            while ((unsigned)(ex >> 32) != (unsigned)t);
            union{unsigned u; float f;} cv; cv.u = (unsigned)ex; hv = cv.f;
          }
        }
        lds_h[tid] = hv;
      } else if (tid < 500){
        int i = tid - 400;               // local row: gate*25 + jj
        int gate = i/25, jj = i - gate*25;
        const unsigned long long* src = gbuf + (size_t)((t+1)&3)*G4 + gate*400 + l*25 + jj;
        unsigned long long ex;
        do { ex = __hip_atomic_load(src, __ATOMIC_RELAXED, __HIP_MEMORY_SCOPE_AGENT); }
        while ((unsigned)(ex >> 32) != (unsigned)(t+1));
        union{unsigned u; float f;} cv; cv.u = (unsigned)ex;
        lds_xg[i] = cv.f;
      }
      __syncthreads();
      float sum = 0.f;
      if (mat){
        const float4* hp = (const float4*)(lds_h + part*100);
        #pragma unroll
        for (int i=0;i<25;i++){
          float4 h4 = hp[i];
          sum += wreg[4*i]*h4.x + wreg[4*i+1]*h4.y + wreg[4*i+2]*h4.z + wreg[4*i+3]*h4.w;
        }
      }
      sum += __shfl_xor(sum, 1);
      sum += __shfl_xor(sum, 2);
      if (mat && part==0) lds_g[row_local] = sum;
      __syncthreads();
      if (ew){
        float gi = lds_xg[tid]    + lds_g[tid];
        float gf = lds_xg[25+tid] + lds_g[25+tid];
        float gg = lds_xg[50+tid] + lds_g[50+tid];
        float go = lds_xg[75+tid] + lds_g[75+tid];
        float si = fsig(gi), sf = fsig(gf), so = fsig(go), tg = ftanh(gg);
        c = sf*c + si*tg;
        float h = so*ftanh(c);
        lds_hnew[tid] = h;
        RN[(size_t)t*HID + j] = h;
        union{unsigned u; float f;} cv; cv.f = h;
        unsigned long long pk = ((unsigned long long)(unsigned)(t+1) << 32) | (unsigned long long)cv.u;
        __hip_atomic_store(hbufB + (size_t)((t+1)&3)*HID + j, pk,
                           __ATOMIC_RELAXED, __HIP_MEMORY_SCOPE_AGENT);
      }
      __syncthreads();
    }
  }
}

// ---------------- rtoken = RN @ fcW.T + fcb  (f32) ----------------
__global__ void __launch_bounds__(256) krtoken(
    const float* __restrict__ RN, const float* __restrict__ fcW,
    const float* __restrict__ fcb, float* __restrict__ out)
{
  __shared__ float xs[8*400];
  const int t0 = blockIdx.x*8;
  const int tid = threadIdx.x;
  for (int idx = tid; idx < 8*400; idx += 256)
    xs[idx] = RN[(size_t)t0*400 + idx];
  __syncthreads();
  if (tid >= 150) return;
  float acc[8];
  #pragma unroll
  for (int i=0;i<8;i++) acc[i]=0.f;
  const float4* wr = (const float4*)(fcW + (size_t)tid*400);
  for (int k4=0;k4<100;k4++){
    float4 w = wr[k4];
    #pragma unroll
    for (int tt=0;tt<8;tt++){
      const float4 x4 = *(const float4*)(xs + tt*400 + 4*k4);
      acc[tt] += w.x*x4.x + w.y*x4.y + w.z*x4.z + w.w*x4.w;
    }
  }
  float bb = fcb[tid];
  #pragma unroll
  for (int tt=0;tt<8;tt++)
    out[(size_t)(t0+tt)*150 + tid] = acc[tt] + bb;
}

// ---------------- per-t context scalar: v[t] = softmax0(actW@rnn+actb) * sigmoid(D@rnn) ----
__global__ void kfinal(const float* __restrict__ RN, const float* __restrict__ actW,
                       const float* __restrict__ actb, const float* __restrict__ Dp,
                       float* __restrict__ vbuf)
{
  int t = blockIdx.x, l = threadIdx.x;
  const float* r = RN + (size_t)t*HID;
  float s0=0.f, s1=0.f, s2=0.f, sd=0.f;
  for (int k=l; k<HID; k+=64){
    float rv = r[k];
    s0 += actW[k]*rv;
    s1 += actW[400+k]*rv;
    s2 += actW[800+k]*rv;
    sd += Dp[k]*rv;
  }
  #pragma unroll
  for (int o=1;o<64;o<<=1){
    s0 += __shfl_xor(s0,o); s1 += __shfl_xor(s1,o);
    s2 += __shfl_xor(s2,o); sd += __shfl_xor(sd,o);
  }
  if (l==0){
    s0 += actb[0]; s1 += actb[1]; s2 += actb[2];
    float m = fmaxf(s0, fmaxf(s1, s2));
    float e0 = __expf(s0-m), e1 = __expf(s1-m), e2 = __expf(s2-m);
    float p0 = e0/(e0+e1+e2);
    vbuf[t] = p0 * fsig(sd);
  }
}

// ---------------- context write: zero everything, slot0 = v[t] broadcast (f32) ----------------
// LAST kernel: deterministically overwrites the whole ctx region (which doubled as scratch).
__global__ void kctx(const float* __restrict__ vbuf, uint4* __restrict__ ctx, int n16){
  int i = blockIdx.x*256 + threadIdx.x;
  int stride = gridDim.x*256;
  for (; i<n16; i+=stride){
    int t = i / 3200;
    int p = i - t*3200;
    uint4 z;
    if (p < 100){
      float v = vbuf[t];
      union{float f; uint32_t u;} cv; cv.f = v;
      z.x = z.y = z.z = z.w = cv.u;
    } else {
      z.x = z.y = z.z = z.w = 0u;
    }
    ctx[i] = z;
  }
}

// ---------------- key LSTM (1 step, h0=c0=0 so key_Whh is dead) + fc (f32) ----------------
__global__ void __launch_bounds__(512) kkey(
    const float* __restrict__ RN, const float* __restrict__ Wih,
    const float* __restrict__ bih, const float* __restrict__ bhh,
    const float* __restrict__ fcW, const float* __restrict__ fcb,
    float* __restrict__ out)
{
  __shared__ float rh[HID];
  __shared__ float gk[4*KDIM];
  __shared__ float hk[KDIM];
  int tid = threadIdx.x;
  if (tid < HID) rh[tid] = RN[(size_t)(T_LEN-1)*HID + tid];
  __syncthreads();
  for (int r = tid; r < 4*KDIM; r += 512){
    const float4* wr = (const float4*)(Wih + (size_t)r*HID);
    float acc = 0.f;
    for (int k4=0;k4<100;k4++){
      float4 w = wr[k4];
      const float4 x4 = *(const float4*)(rh + 4*k4);
      acc += w.x*x4.x + w.y*x4.y + w.z*x4.z + w.w*x4.w;
    }
    gk[r] = acc + bih[r] + bhh[r];
  }
  __syncthreads();
  if (tid < KDIM){
    float gi = gk[tid], gg = gk[2*KDIM+tid], go = gk[3*KDIM+tid];
    float cc = fsig(gi)*ftanh(gg);        // c0 = 0 -> forget-gate term vanishes
    hk[tid] = fsig(go)*ftanh(cc);
  }
  __syncthreads();
  if (tid < HID){
    const float4* wr = (const float4*)(fcW + (size_t)tid*KDIM);
    float acc = 0.f;
    for (int k4=0;k4<75;k4++){
      float4 w = wr[k4];
      const float4 x4 = *(const float4*)(hk + 4*k4);
      acc += w.x*x4.x + w.y*x4.y + w.z*x4.z + w.w*x4.w;
    }
    out[tid] = acc + fcb[tid];
  }
}

extern "C" void kernel_launch(void* const* d_in, const int* in_sizes, int n_in,
                              void* d_out, int out_size, void* d_ws, size_t ws_size,
                              hipStream_t stream)
{
  (void)in_sizes; (void)n_in; (void)ws_size;
  const int*   xr   = (const int*)d_in[0];
  const int*   xcpc = (const int*)d_in[1];
  const int*   xma  = (const int*)d_in[2];
  const float* em   = (const float*)d_in[3];
  const float* ec   = (const float*)d_in[4];
  const float* er   = (const float*)d_in[5];
  const float* Wih0 = (const float*)d_in[6];
  const float* Whh0 = (const float*)d_in[7];
  const float* bih0 = (const float*)d_in[8];
  const float* bhh0 = (const float*)d_in[9];
  const float* Wih1 = (const float*)d_in[10];
  const float* Whh1 = (const float*)d_in[11];
  const float* bih1 = (const float*)d_in[12];
  const float* bhh1 = (const float*)d_in[13];
  const float* fcW  = (const float*)d_in[14];
  const float* fcb  = (const float*)d_in[15];
  const float* actW = (const float*)d_in[16];
  const float* actb = (const float*)d_in[17];
  const float* Dp   = (const float*)d_in[18];
  const float* kWih = (const float*)d_in[19];
  /* d_in[20] key_Whh unused: h0 = 0 for the single key step */
  const float* kbih = (const float*)d_in[21];
  const float* kbhh = (const float*)d_in[22];
  const float* kfcW = (const float*)d_in[23];
  const float* kfcb = (const float*)d_in[24];

  // ---- vbuf stays in ws (kctx both reads vbuf and rewrites the ctx region) ----
  float* vbuf = (float*)d_ws;                           // 16 KB

  // ---- large scratch + handshake bufs in TAIL of d_out's ctx region (kctx rewrites last) ----
  float* out = (float*)d_out;
  char*  ob  = (char*)d_out;
  size_t total = (size_t)out_size * 4;                  // 212,174,400 bytes
  float* XG0 = (float*)(ob + total - 26214400);         // 4096*1600 f32
  float* RN  = (float*)(ob + total - 32768000);         // 4096*400 f32
  char*  ctl = ob + total - 32768000 - 131072;          // control block (128 KB reserve)
  unsigned long long* hbufA = (unsigned long long*)(ctl);          // 4*400*8 = 12,800 B
  unsigned long long* hbufB = (unsigned long long*)(ctl + 12800);  // 12,800 B
  unsigned long long* gbuf  = (unsigned long long*)(ctl + 25600);  // 4*1600*8 = 51,200 B

  float* rtok = out;                 // 4096*150
  float* ktok = out + 614400;        // 400
  uint4* ctxp = (uint4*)(ob + 614800u*4u);              // ctx region, 209,715,200 B
  int n16 = (int)((total - 614800u*4u) >> 4);           // 13,107,200

  dim3 gg(T_LEN/8, 7);
  kgemm0<<<gg,256,0,stream>>>(xma, xcpc, xr, em, ec, er, Wih0, bih0, bhh0, XG0);
  kpipe<<<48,512,0,stream>>>(XG0, Whh0, Whh1, Wih1, bih1, bhh1, RN,
                             hbufA, hbufB, gbuf, T_LEN);
  krtoken<<<T_LEN/8,256,0,stream>>>(RN, fcW, fcb, rtok);
  kkey<<<1,512,0,stream>>>(RN, kWih, kbih, kbhh, kfcW, kfcb, ktok);
  kfinal<<<T_LEN,64,0,stream>>>(RN, actW, actb, Dp, vbuf);
  kctx<<<2048,256,0,stream>>>(vbuf, ctxp, n16);
}